// Round 5
// baseline (1021.602 us; speedup 1.0000x reference)
//
#include <hip/hip_runtime.h>

#define BB 8
#define CC 256
#define TT 4
#define NNv 4096
#define HH 1024
#define LLv (TT*NNv)   // 16384

typedef short bf16x8 __attribute__((ext_vector_type(8)));
typedef float f32x4 __attribute__((ext_vector_type(4)));

static __device__ __forceinline__ float bfbits2f(unsigned short h) {
    return __uint_as_float(((unsigned int)h) << 16);
}
static __device__ __forceinline__ unsigned short f2bf(float f) {
    unsigned int u = __float_as_uint(f);
    return (unsigned short)((u + 0x7FFFu + ((u >> 16) & 1u)) >> 16);
}
// source byte j within a group of 8 lands at fragment slot permpos(j);
// slot p holds source byte perm8[p], perm8 = {0,2,4,6,1,3,5,7}.
static __device__ __forceinline__ int permpos(int j) { return (j >> 1) + ((j & 1) << 2); }

// ---- fc1 weights -> fragment-linear 3-split (hi/mid/lo), k-permuted ----
__global__ __launch_bounds__(256) void k_prep1(const float* __restrict__ w,
                                               unsigned short* __restrict__ wf)
{
    int i = blockIdx.x * 256 + threadIdx.x;        // i = h*256 + c
    int h = i >> 8, c = i & 255;
    int ht = h >> 6, hr = h & 63, g = hr >> 4, ln = hr & 15;
    int ko = c >> 6, cr = c & 63, kb = cr >> 5, q = (cr >> 3) & 3, j = c & 7;
    size_t base = (((((size_t)ht * 4 + ko) * 2 + kb) * 4 + g) * 64 + q * 16 + ln) * 8 + permpos(j);
    const size_t WS = 262144;
    float x = w[i];
    unsigned short hi = f2bf(x); float r  = __fsub_rn(x, bfbits2f(hi));
    unsigned short md = f2bf(r); float r2 = __fsub_rn(r, bfbits2f(md));
    unsigned short lo = f2bf(r2);
    wf[base] = hi; wf[WS + base] = md; wf[2 * WS + base] = lo;
}

// ---- fc2 weights -> fragment-linear 2-split (hi/lo), k-permuted ----
__global__ __launch_bounds__(256) void k_prep2(const float* __restrict__ w,
                                               unsigned short* __restrict__ wf)
{
    int i = blockIdx.x * 256 + threadIdx.x;        // i = c*1024 + h
    int c = i >> 10, h = i & 1023;
    int ct = c >> 6, cr = c & 63, g = cr >> 4, ln = cr & 15;
    int ko = h >> 7, hr = h & 127, kb = hr >> 5, q = (hr >> 3) & 3, j = h & 7;
    size_t base = (((((size_t)ct * 8 + ko) * 4 + kb) * 4 + g) * 64 + q * 16 + ln) * 8 + permpos(j);
    const size_t WS = 262144;
    float x = w[i];
    unsigned short hi = f2bf(x); float r = __fsub_rn(x, bfbits2f(hi));
    unsigned short lo = f2bf(r);
    wf[base] = hi; wf[WS + base] = lo;
}

// ---- bn2 + LIF + transpose: x[b][c][t][n] -> s1b[b][t][n][c] bf16 {0,1}, c k-permuted ----
__global__ __launch_bounds__(256) void k_bn2_lif_t(
    const float* __restrict__ x,
    const float* __restrict__ g, const float* __restrict__ be,
    const float* __restrict__ mu, const float* __restrict__ va,
    unsigned short* __restrict__ s1b)
{
    __shared__ unsigned char ts[TT][64][80];       // [t][c][n], stride 80
    int tx = threadIdx.x;
    int n0 = blockIdx.x * 64;
    int c0 = blockIdx.y * 64;
    int b  = blockIdx.z;
    int cl = tx >> 2, np = tx & 3;
    int c = c0 + cl;
    float rsq = __fdiv_rn(1.0f, __fsqrt_rn(__fadd_rn(va[c], 1e-5f)));
    float inv = __fmul_rn(g[c], rsq);
    float add = __fsub_rn(be[c], __fmul_rn(mu[c], inv));
    size_t xb = ((size_t)(b * CC + c) * TT) * NNv + n0 + np * 16;
    float v[16];
    #pragma unroll
    for (int i = 0; i < 16; i++) v[i] = 0.0f;
    #pragma unroll
    for (int t = 0; t < TT; t++) {
        float4 p[4];
        #pragma unroll
        for (int k = 0; k < 4; k++) p[k] = *(const float4*)(x + xb + (size_t)t * NNv + 4 * k);
        const float* xp = (const float*)p;
        unsigned int ob[4] = {0, 0, 0, 0};
        #pragma unroll
        for (int i = 0; i < 16; i++) {
            float y = __fadd_rn(__fmul_rn(xp[i], inv), add);
            float vv = __fadd_rn(v[i], __fdiv_rn(__fsub_rn(y, v[i]), 1.5f));
            bool sp = vv >= 1.0f;
            v[i] = sp ? 0.0f : vv;
            if (sp) ob[i >> 2] |= 1u << (8 * (i & 3));
        }
        uint4 pk; pk.x = ob[0]; pk.y = ob[1]; pk.z = ob[2]; pk.w = ob[3];
        *(uint4*)&ts[t][cl][np * 16] = pk;
    }
    __syncthreads();
    int nl = tx >> 2, cp = tx & 3;
    const int perm8[8] = {0, 2, 4, 6, 1, 3, 5, 7};
    #pragma unroll
    for (int t = 0; t < TT; t++) {
        unsigned short sh[16];
        #pragma unroll
        for (int p = 0; p < 16; p++)
            sh[p] = ts[t][cp * 16 + (p & 8) + perm8[p & 7]][nl] ? 0x3F80 : 0;
        unsigned short* op = s1b + ((size_t)(b * TT + t) * NNv + n0 + nl) * CC + c0 + cp * 16;
        *(uint4*)op = *(uint4*)&sh[0];
        *(uint4*)(op + 8) = *(uint4*)&sh[8];
    }
}

// ------- GEMM1 (fc1): LDS-free, frags direct from global; fused bias+bn1+LIF -> s2b bf16 -------
__global__ __launch_bounds__(256, 3) void k_gemm1_lif(
    const unsigned short* __restrict__ w1f,
    const float* __restrict__ b1,
    const float* __restrict__ g1, const float* __restrict__ be1,
    const float* __restrict__ mu1, const float* __restrict__ va1,
    const unsigned short* __restrict__ s1b, unsigned short* __restrict__ s2b, int boff)
{
    const int tx = threadIdx.x;
    const int ht = blockIdx.x;              // fastest: 16 blocks share one spike region (L2)
    const int n0 = blockIdx.y * 64;
    const int bl = blockIdx.z;              // local batch 0..1
    const int b  = boff + bl;
    const int lane = tx & 63, w = tx >> 6;
    const int q = lane >> 4, ln = lane & 15;
    const int mh = (w & 1) * 32, wn = (w >> 1) * 32;
    const int h0 = ht * 64;
    const size_t WS = 262144;

    f32x4 acc[TT][2][2];
    #pragma unroll
    for (int t = 0; t < TT; t++)
    #pragma unroll
    for (int mi = 0; mi < 2; mi++)
    #pragma unroll
    for (int ni = 0; ni < 2; ni++)
        acc[t][mi][ni] = (f32x4){0.f, 0.f, 0.f, 0.f};

    #pragma unroll
    for (int ko = 0; ko < 4; ko++) {
        #pragma unroll
        for (int kb = 0; kb < 2; kb++) {
            bf16x8 wf[2][3];
            #pragma unroll
            for (int mi = 0; mi < 2; mi++) {
                int gg = (mh >> 4) + mi;
                size_t fb = (((((size_t)ht * 4 + ko) * 2 + kb) * 4 + gg) * 64 + lane) * 8;
                #pragma unroll
                for (int s = 0; s < 3; s++)
                    wf[mi][s] = *(const bf16x8*)(w1f + s * WS + fb);
            }
            #pragma unroll
            for (int t = 0; t < TT; t++) {
                const unsigned short* bp = s1b
                    + ((size_t)(b * TT + t) * NNv + n0 + wn) * CC + ko * 64 + kb * 32 + q * 8;
                bf16x8 sf0 = *(const bf16x8*)(bp + ln * CC);
                bf16x8 sf1 = *(const bf16x8*)(bp + (16 + ln) * CC);
                #pragma unroll
                for (int s = 0; s < 3; s++) {
                    acc[t][0][0] = __builtin_amdgcn_mfma_f32_16x16x32_bf16(wf[0][s], sf0, acc[t][0][0], 0, 0, 0);
                    acc[t][0][1] = __builtin_amdgcn_mfma_f32_16x16x32_bf16(wf[0][s], sf1, acc[t][0][1], 0, 0, 0);
                    acc[t][1][0] = __builtin_amdgcn_mfma_f32_16x16x32_bf16(wf[1][s], sf0, acc[t][1][0], 0, 0, 0);
                    acc[t][1][1] = __builtin_amdgcn_mfma_f32_16x16x32_bf16(wf[1][s], sf1, acc[t][1][1], 0, 0, 0);
                }
            }
        }
    }

    // epilogue: bias + bn1 + LIF scan; write bf16 spikes (h k-permuted) to s2b[bl][l][h]
    #pragma unroll
    for (int mi = 0; mi < 2; mi++) {
        float invr[4], addr_[4], biasr[4];
        #pragma unroll
        for (int r = 0; r < 4; r++) {
            int h = h0 + mh + mi * 16 + q * 4 + r;
            float rsq = __fdiv_rn(1.0f, __fsqrt_rn(__fadd_rn(va1[h], 1e-5f)));
            invr[r] = __fmul_rn(g1[h], rsq);
            addr_[r] = __fsub_rn(be1[h], __fmul_rn(mu1[h], invr[r]));
            biasr[r] = b1[h];
        }
        int hgrp = h0 + mh + mi * 16 + (q >> 1) * 8;   // 8-aligned h-group base
        int hsub = (q & 1) * 2;
        #pragma unroll
        for (int ni = 0; ni < 2; ni++) {
            int l_n = n0 + wn + ni * 16 + ln;
            float v4[4] = {0.f, 0.f, 0.f, 0.f};
            #pragma unroll
            for (int t = 0; t < TT; t++) {
                unsigned short sv[4];
                #pragma unroll
                for (int r = 0; r < 4; r++) {
                    float h1 = __fadd_rn(acc[t][mi][ni][r], biasr[r]);
                    float y  = __fadd_rn(__fmul_rn(h1, invr[r]), addr_[r]);
                    float vv = __fadd_rn(v4[r], __fdiv_rn(__fsub_rn(y, v4[r]), 1.5f));
                    bool sp = vv >= 1.0f;
                    v4[r] = sp ? 0.0f : vv;
                    sv[r] = sp ? 0x3F80 : 0;
                }
                unsigned short* op = s2b + ((size_t)bl * LLv + t * NNv + l_n) * HH + hgrp + hsub;
                // slots: (r0,r2) at +0, (r1,r3) at +4 (within the 8-group, see permpos)
                *(unsigned int*)op       = (unsigned int)sv[0] | ((unsigned int)sv[2] << 16);
                *(unsigned int*)(op + 4) = (unsigned int)sv[1] | ((unsigned int)sv[3] << 16);
            }
        }
    }
}

// ------- GEMM2 (fc2): LDS-free, frags direct from global; bias + fp32 out -------
__global__ __launch_bounds__(256, 4) void k_gemm2(
    const unsigned short* __restrict__ w2f,
    const float* __restrict__ b2c,
    const unsigned short* __restrict__ s2b, float* __restrict__ outp, int boff)
{
    const int tx = threadIdx.x;
    const int ct = blockIdx.x;              // fastest: 4 blocks share one spike region (L2)
    const int l0 = blockIdx.y * 128;
    const int bl = blockIdx.z;
    const int b  = boff + bl;
    const int lane = tx & 63, w = tx >> 6;
    const int q = lane >> 4, ln = lane & 15;
    const int mc = (w & 1) * 32, wl = (w >> 1) * 64;
    const size_t WS = 262144;

    f32x4 acc[2][4];
    #pragma unroll
    for (int mi = 0; mi < 2; mi++)
    #pragma unroll
    for (int ni = 0; ni < 4; ni++)
        acc[mi][ni] = (f32x4){0.f, 0.f, 0.f, 0.f};

    #pragma unroll
    for (int ko = 0; ko < 8; ko++) {
        #pragma unroll
        for (int kb = 0; kb < 4; kb++) {
            bf16x8 wf[2][2];
            #pragma unroll
            for (int mi = 0; mi < 2; mi++) {
                int gg = (mc >> 4) + mi;
                size_t fb = (((((size_t)ct * 8 + ko) * 4 + kb) * 4 + gg) * 64 + lane) * 8;
                #pragma unroll
                for (int s = 0; s < 2; s++)
                    wf[mi][s] = *(const bf16x8*)(w2f + s * WS + fb);
            }
            bf16x8 sf[4];
            const unsigned short* bp = s2b
                + ((size_t)bl * LLv + l0 + wl) * HH + ko * 128 + kb * 32 + q * 8;
            #pragma unroll
            for (int ni = 0; ni < 4; ni++)
                sf[ni] = *(const bf16x8*)(bp + (ni * 16 + ln) * HH);
            #pragma unroll
            for (int s = 0; s < 2; s++)
            #pragma unroll
            for (int mi = 0; mi < 2; mi++)
            #pragma unroll
            for (int ni = 0; ni < 4; ni++)
                acc[mi][ni] = __builtin_amdgcn_mfma_f32_16x16x32_bf16(wf[mi][s], sf[ni], acc[mi][ni], 0, 0, 0);
        }
    }
    #pragma unroll
    for (int mi = 0; mi < 2; mi++)
    #pragma unroll
    for (int r = 0; r < 4; r++) {
        int c = ct * 64 + mc + mi * 16 + q * 4 + r;
        float bias = b2c[c];
        #pragma unroll
        for (int ni = 0; ni < 4; ni++) {
            int l = l0 + wl + ni * 16 + ln;
            outp[((size_t)b * CC + c) * LLv + l] = __fadd_rn(acc[mi][ni][r], bias);
        }
    }
}

extern "C" void kernel_launch(void* const* d_in, const int* in_sizes, int n_in,
                              void* d_out, int out_size, void* d_ws, size_t ws_size,
                              hipStream_t stream) {
    const float* x    = (const float*)d_in[0];
    const float* fc1w = (const float*)d_in[1];
    const float* fc1b = (const float*)d_in[2];
    const float* fc2w = (const float*)d_in[3];
    const float* fc2b = (const float*)d_in[4];
    const float* g1   = (const float*)d_in[5];
    const float* be1  = (const float*)d_in[6];
    const float* mu1  = (const float*)d_in[7];
    const float* va1  = (const float*)d_in[8];
    const float* g2   = (const float*)d_in[9];
    const float* be2  = (const float*)d_in[10];
    const float* mu2  = (const float*)d_in[11];
    const float* va2  = (const float*)d_in[12];

    const size_t WS = 262144;
    unsigned short* w1f = (unsigned short*)d_ws;              // 3*WS shorts
    unsigned short* w2f = w1f + 3 * WS;                       // 2*WS shorts
    unsigned short* s1b = w2f + 2 * WS;                       // B*C*L bf16 = 67 MB
    unsigned short* s2b = s1b + (size_t)BB * CC * LLv;        // 2*L*H bf16 = 67 MB (per 2-batch chunk)
    float* outp = (float*)d_out;

    hipLaunchKernelGGL(k_prep1, dim3(1024), dim3(256), 0, stream, fc1w, w1f);
    hipLaunchKernelGGL(k_prep2, dim3(1024), dim3(256), 0, stream, fc2w, w2f);
    hipLaunchKernelGGL(k_bn2_lif_t, dim3(NNv / 64, CC / 64, BB), dim3(256), 0, stream,
                       x, g2, be2, mu2, va2, s1b);
    for (int boff = 0; boff < BB; boff += 2) {
        hipLaunchKernelGGL(k_gemm1_lif, dim3(HH / 64, NNv / 64, 2), dim3(256), 0, stream,
                           w1f, fc1b, g1, be1, mu1, va1, s1b, s2b, boff);
        hipLaunchKernelGGL(k_gemm2, dim3(CC / 64, LLv / 128, 2), dim3(256), 0, stream,
                           w2f, fc2b, s2b, outp, boff);
    }
}

// Round 6
// 746.685 us; speedup vs baseline: 1.3682x; 1.3682x over previous
//
#include <hip/hip_runtime.h>

#define BB 8
#define CC 256
#define TT 4
#define NNv 4096
#define HH 1024
#define LLv (TT*NNv)   // 16384

typedef short bf16x8 __attribute__((ext_vector_type(8)));
typedef float f32x4 __attribute__((ext_vector_type(4)));

#define AS1 __attribute__((address_space(1)))
#define AS3 __attribute__((address_space(3)))

static __device__ __forceinline__ float bfbits2f(unsigned short h) {
    return __uint_as_float(((unsigned int)h) << 16);
}
static __device__ __forceinline__ unsigned short f2bf(float f) {
    unsigned int u = __float_as_uint(f);
    return (unsigned short)((u + 0x7FFFu + ((u >> 16) & 1u)) >> 16);
}
// async 16B global->LDS (direct-to-shared DMA, no VGPR round-trip).
// LDS dest is wave-uniform base + lane*16.
static __device__ __forceinline__ void gl_lds16(const unsigned short* g, unsigned short* l) {
    __builtin_amdgcn_global_load_lds((AS1 const unsigned int*)g, (AS3 unsigned int*)l, 16, 0, 0);
}

// ---- fc1 weights -> fragment-linear 3-split (hi/mid/lo) ----
// dst: ((((ht*4+ko)*2+kb)*4+g)*64 + q*16+ln)*8 + j   (+ s*262144)
__global__ __launch_bounds__(256) void k_prep1(const float* __restrict__ w,
                                               unsigned short* __restrict__ wf)
{
    int i = blockIdx.x * 256 + threadIdx.x;        // i = h*256 + c
    int h = i >> 8, c = i & 255;
    int ht = h >> 6, hr = h & 63, g = hr >> 4, ln = hr & 15;
    int ko = c >> 6, cr = c & 63, kb = cr >> 5, q = (cr >> 3) & 3, j = c & 7;
    size_t base = (((((size_t)ht * 4 + ko) * 2 + kb) * 4 + g) * 64 + q * 16 + ln) * 8 + j;
    const size_t WS = 262144;
    float x = w[i];
    unsigned short hi = f2bf(x); float r  = __fsub_rn(x, bfbits2f(hi));
    unsigned short md = f2bf(r); float r2 = __fsub_rn(r, bfbits2f(md));
    unsigned short lo = f2bf(r2);
    wf[base] = hi; wf[WS + base] = md; wf[2 * WS + base] = lo;
}

// ---- fc2 weights -> fragment-linear 2-split (hi/lo) ----
// dst: ((((ct*8+ko)*4+kb)*4+g)*64 + q*16+ln)*8 + j   (+ s*262144)
__global__ __launch_bounds__(256) void k_prep2(const float* __restrict__ w,
                                               unsigned short* __restrict__ wf)
{
    int i = blockIdx.x * 256 + threadIdx.x;        // i = c*1024 + h
    int c = i >> 10, h = i & 1023;
    int ct = c >> 6, cr = c & 63, g = cr >> 4, ln = cr & 15;
    int ko = h >> 7, hr = h & 127, kb = hr >> 5, q = (hr >> 3) & 3, j = h & 7;
    size_t base = (((((size_t)ct * 8 + ko) * 4 + kb) * 4 + g) * 64 + q * 16 + ln) * 8 + j;
    const size_t WS = 262144;
    float x = w[i];
    unsigned short hi = f2bf(x); float r = __fsub_rn(x, bfbits2f(hi));
    unsigned short lo = f2bf(r);
    wf[base] = hi; wf[WS + base] = lo;
}

// ---- bn2 + LIF + transpose: x[b][c][t][n] -> s1b[b][t][ko4][n][64] bf16 {0,1} ----
__global__ __launch_bounds__(256) void k_bn2_lif_t(
    const float* __restrict__ x,
    const float* __restrict__ g, const float* __restrict__ be,
    const float* __restrict__ mu, const float* __restrict__ va,
    unsigned short* __restrict__ s1b)
{
    __shared__ unsigned char ts[TT][64][80];       // [t][c][n], stride 80
    int tx = threadIdx.x;
    int n0 = blockIdx.x * 64;
    int c0 = blockIdx.y * 64;
    int b  = blockIdx.z;
    int cl = tx >> 2, np = tx & 3;
    int c = c0 + cl;
    float rsq = __fdiv_rn(1.0f, __fsqrt_rn(__fadd_rn(va[c], 1e-5f)));
    float inv = __fmul_rn(g[c], rsq);
    float add = __fsub_rn(be[c], __fmul_rn(mu[c], inv));
    size_t xb = ((size_t)(b * CC + c) * TT) * NNv + n0 + np * 16;
    float v[16];
    #pragma unroll
    for (int i = 0; i < 16; i++) v[i] = 0.0f;
    #pragma unroll
    for (int t = 0; t < TT; t++) {
        float4 p[4];
        #pragma unroll
        for (int k = 0; k < 4; k++) p[k] = *(const float4*)(x + xb + (size_t)t * NNv + 4 * k);
        const float* xp = (const float*)p;
        unsigned int ob[4] = {0, 0, 0, 0};
        #pragma unroll
        for (int i = 0; i < 16; i++) {
            float y = __fadd_rn(__fmul_rn(xp[i], inv), add);
            float vv = __fadd_rn(v[i], __fdiv_rn(__fsub_rn(y, v[i]), 1.5f));
            bool sp = vv >= 1.0f;
            v[i] = sp ? 0.0f : vv;
            if (sp) ob[i >> 2] |= 1u << (8 * (i & 3));
        }
        uint4 pk; pk.x = ob[0]; pk.y = ob[1]; pk.z = ob[2]; pk.w = ob[3];
        *(uint4*)&ts[t][cl][np * 16] = pk;
    }
    __syncthreads();
    int nl = tx >> 2, cp = tx & 3;
    #pragma unroll
    for (int t = 0; t < TT; t++) {
        unsigned short sh[16];
        #pragma unroll
        for (int p = 0; p < 16; p++)
            sh[p] = ts[t][cp * 16 + p][nl] ? 0x3F80 : 0;
        // layout: [b][t][ko=c0>>6][n][64c], inner offset cp*16
        unsigned short* op = s1b + ((((size_t)(b * TT + t) * 4) + (c0 >> 6)) * NNv + n0 + nl) * 64 + cp * 16;
        *(uint4*)op = *(uint4*)&sh[0];
        *(uint4*)(op + 8) = *(uint4*)&sh[8];
    }
}

// ------- GEMM1 (fc1) 3-split; async bf16 spike staging, XOR-swizzled LDS; fused bn1+LIF -------
__global__ __launch_bounds__(256, 4) void k_gemm1_lif(
    const unsigned short* __restrict__ w1f,
    const float* __restrict__ b1,
    const float* __restrict__ g1, const float* __restrict__ be1,
    const float* __restrict__ mu1, const float* __restrict__ va1,
    const unsigned short* __restrict__ s1b, unsigned short* __restrict__ s2b, int boff)
{
    __shared__ unsigned short Ss[TT * 64 * 64];    // [t][n][64c] = 32 KB, chunk^=(n&7) swizzle
    const int tx = threadIdx.x;
    const int ht = blockIdx.x;              // fastest: 16 blocks share one spike region (L2)
    const int n0 = blockIdx.y * 64;
    const int bl = blockIdx.z;              // local batch 0..1
    const int b  = boff + bl;
    const int lane = tx & 63, w = tx >> 6;
    const int q = lane >> 4, ln = lane & 15;
    const int mh = (w & 1) * 32, wn = (w >> 1) * 32;
    const int h0 = ht * 64;
    const size_t WS = 262144;

    // staging source params (wave w stages t=w; 8 issues of 8 rows x 128B)
    const int st_n  = lane >> 3;                       // row-in-group 0..7
    const int st_ck = (lane & 7) ^ st_n;               // swizzled source chunk
    const unsigned short* st_base = s1b + st_ck * 8;

    f32x4 acc[TT][2][2];
    #pragma unroll
    for (int t = 0; t < TT; t++)
    #pragma unroll
    for (int mi = 0; mi < 2; mi++)
    #pragma unroll
    for (int ni = 0; ni < 2; ni++)
        acc[t][mi][ni] = (f32x4){0.f, 0.f, 0.f, 0.f};

    for (int ko = 0; ko < 4; ko++) {
        __syncthreads();
        #pragma unroll
        for (int it = 0; it < 8; it++) {
            const unsigned short* gp = st_base
                + ((((size_t)b * 4 + w) * 4 + ko) * NNv + n0 + it * 8 + st_n) * 64;
            gl_lds16(gp, &Ss[(w * 8 + it) * 512]);
        }
        __syncthreads();
        #pragma unroll
        for (int kb = 0; kb < 2; kb++) {
            bf16x8 wf[2][3];
            #pragma unroll
            for (int mi = 0; mi < 2; mi++) {
                int gg = (mh >> 4) + mi;
                size_t fb = (((((size_t)ht * 4 + ko) * 2 + kb) * 4 + gg) * 64 + lane) * 8;
                #pragma unroll
                for (int s = 0; s < 3; s++)
                    wf[mi][s] = *(const bf16x8*)(w1f + s * WS + fb);
            }
            #pragma unroll
            for (int t = 0; t < TT; t++) {
                int ck = ((kb * 4 + q) ^ (ln & 7)) * 8;
                bf16x8 sf0 = *(const bf16x8*)&Ss[(t * 64 + wn + ln) * 64 + ck];
                bf16x8 sf1 = *(const bf16x8*)&Ss[(t * 64 + wn + 16 + ln) * 64 + ck];
                #pragma unroll
                for (int s = 0; s < 3; s++) {
                    acc[t][0][0] = __builtin_amdgcn_mfma_f32_16x16x32_bf16(wf[0][s], sf0, acc[t][0][0], 0, 0, 0);
                    acc[t][0][1] = __builtin_amdgcn_mfma_f32_16x16x32_bf16(wf[0][s], sf1, acc[t][0][1], 0, 0, 0);
                    acc[t][1][0] = __builtin_amdgcn_mfma_f32_16x16x32_bf16(wf[1][s], sf0, acc[t][1][0], 0, 0, 0);
                    acc[t][1][1] = __builtin_amdgcn_mfma_f32_16x16x32_bf16(wf[1][s], sf1, acc[t][1][1], 0, 0, 0);
                }
            }
        }
    }

    // epilogue: bias + bn1 + LIF scan; write bf16 spikes to s2b[bl][ko8][l][128h]
    #pragma unroll
    for (int mi = 0; mi < 2; mi++) {
        float invr[4], addr_[4], biasr[4];
        #pragma unroll
        for (int r = 0; r < 4; r++) {
            int h = h0 + mh + mi * 16 + q * 4 + r;
            float rsq = __fdiv_rn(1.0f, __fsqrt_rn(__fadd_rn(va1[h], 1e-5f)));
            invr[r] = __fmul_rn(g1[h], rsq);
            addr_[r] = __fsub_rn(be1[h], __fmul_rn(mu1[h], invr[r]));
            biasr[r] = b1[h];
        }
        int hin = (ht & 1) * 64 + mh + mi * 16 + q * 4;   // offset within 128-h chunk
        #pragma unroll
        for (int ni = 0; ni < 2; ni++) {
            int l_n = n0 + wn + ni * 16 + ln;
            float v4[4] = {0.f, 0.f, 0.f, 0.f};
            #pragma unroll
            for (int t = 0; t < TT; t++) {
                unsigned short sv[4];
                #pragma unroll
                for (int r = 0; r < 4; r++) {
                    float h1 = __fadd_rn(acc[t][mi][ni][r], biasr[r]);
                    float y  = __fadd_rn(__fmul_rn(h1, invr[r]), addr_[r]);
                    float vv = __fadd_rn(v4[r], __fdiv_rn(__fsub_rn(y, v4[r]), 1.5f));
                    bool sp = vv >= 1.0f;
                    v4[r] = sp ? 0.0f : vv;
                    sv[r] = sp ? 0x3F80 : 0;
                }
                unsigned short* op = s2b
                    + (((size_t)bl * 8 + (ht >> 1)) * LLv + t * NNv + l_n) * 128 + hin;
                uint2 pk;
                pk.x = (unsigned int)sv[0] | ((unsigned int)sv[1] << 16);
                pk.y = (unsigned int)sv[2] | ((unsigned int)sv[3] << 16);
                *(uint2*)op = pk;
            }
        }
    }
}

// ------- GEMM2 (fc2) 2-split; async bf16 spike staging, XOR-swizzled LDS; bias + fp32 out -------
__global__ __launch_bounds__(256, 4) void k_gemm2(
    const unsigned short* __restrict__ w2f,
    const float* __restrict__ b2c,
    const unsigned short* __restrict__ s2b, float* __restrict__ outp, int boff)
{
    __shared__ unsigned short Ss[128 * 128];   // [l][128h] = 32 KB, chunk^=(l&7) swizzle
    const int tx = threadIdx.x;
    const int ct = blockIdx.x;              // fastest: 4 blocks share one spike region (L2)
    const int l0 = blockIdx.y * 128;
    const int bl = blockIdx.z;
    const int b  = boff + bl;
    const int lane = tx & 63, w = tx >> 6;
    const int q = lane >> 4, ln = lane & 15;
    const int mc = (w & 1) * 32, wl = (w >> 1) * 64;
    const size_t WS = 262144;

    f32x4 acc[2][4];
    #pragma unroll
    for (int mi = 0; mi < 2; mi++)
    #pragma unroll
    for (int ni = 0; ni < 4; ni++)
        acc[mi][ni] = (f32x4){0.f, 0.f, 0.f, 0.f};

    const int st_r = lane >> 4;                        // row-in-group 0..3
    for (int ko = 0; ko < 8; ko++) {
        __syncthreads();
        #pragma unroll
        for (int it = 0; it < 8; it++) {
            int u = w * 8 + it;
            int r = 4 * u + st_r;                      // row 0..127
            int ck = (lane & 15) ^ (r & 7);            // swizzled source chunk
            const unsigned short* gp = s2b
                + (((size_t)bl * 8 + ko) * LLv + l0 + r) * 128 + ck * 8;
            gl_lds16(gp, &Ss[u * 512]);
        }
        __syncthreads();
        #pragma unroll
        for (int kb = 0; kb < 4; kb++) {
            bf16x8 wf[2][2];
            #pragma unroll
            for (int mi = 0; mi < 2; mi++) {
                int gg = (mc >> 4) + mi;
                size_t fb = (((((size_t)ct * 8 + ko) * 4 + kb) * 4 + gg) * 64 + lane) * 8;
                #pragma unroll
                for (int s = 0; s < 2; s++)
                    wf[mi][s] = *(const bf16x8*)(w2f + s * WS + fb);
            }
            bf16x8 sf[4];
            #pragma unroll
            for (int ni = 0; ni < 4; ni++) {
                int row = wl + ni * 16 + ln;
                int ck = ((kb * 4 + q) ^ (ln & 7)) * 8;
                sf[ni] = *(const bf16x8*)&Ss[row * 128 + ck];
            }
            #pragma unroll
            for (int s = 0; s < 2; s++)
            #pragma unroll
            for (int mi = 0; mi < 2; mi++)
            #pragma unroll
            for (int ni = 0; ni < 4; ni++)
                acc[mi][ni] = __builtin_amdgcn_mfma_f32_16x16x32_bf16(wf[mi][s], sf[ni], acc[mi][ni], 0, 0, 0);
        }
    }
    #pragma unroll
    for (int mi = 0; mi < 2; mi++)
    #pragma unroll
    for (int r = 0; r < 4; r++) {
        int c = ct * 64 + mc + mi * 16 + q * 4 + r;
        float bias = b2c[c];
        #pragma unroll
        for (int ni = 0; ni < 4; ni++) {
            int l = l0 + wl + ni * 16 + ln;
            outp[((size_t)b * CC + c) * LLv + l] = __fadd_rn(acc[mi][ni][r], bias);
        }
    }
}

extern "C" void kernel_launch(void* const* d_in, const int* in_sizes, int n_in,
                              void* d_out, int out_size, void* d_ws, size_t ws_size,
                              hipStream_t stream) {
    const float* x    = (const float*)d_in[0];
    const float* fc1w = (const float*)d_in[1];
    const float* fc1b = (const float*)d_in[2];
    const float* fc2w = (const float*)d_in[3];
    const float* fc2b = (const float*)d_in[4];
    const float* g1   = (const float*)d_in[5];
    const float* be1  = (const float*)d_in[6];
    const float* mu1  = (const float*)d_in[7];
    const float* va1  = (const float*)d_in[8];
    const float* g2   = (const float*)d_in[9];
    const float* be2  = (const float*)d_in[10];
    const float* mu2  = (const float*)d_in[11];
    const float* va2  = (const float*)d_in[12];

    const size_t WS = 262144;
    unsigned short* w1f = (unsigned short*)d_ws;              // 1.5 MB
    unsigned short* w2f = w1f + 3 * WS;                       // 1 MB
    unsigned short* s1b = w2f + 2 * WS;                       // 67 MB bf16 spikes (layer 1)
    unsigned short* s2b = s1b + (size_t)BB * CC * LLv;        // 67 MB bf16 spikes (2-batch chunk)
    float* outp = (float*)d_out;

    hipLaunchKernelGGL(k_prep1, dim3(1024), dim3(256), 0, stream, fc1w, w1f);
    hipLaunchKernelGGL(k_prep2, dim3(1024), dim3(256), 0, stream, fc2w, w2f);
    hipLaunchKernelGGL(k_bn2_lif_t, dim3(NNv / 64, CC / 64, BB), dim3(256), 0, stream,
                       x, g2, be2, mu2, va2, s1b);
    for (int boff = 0; boff < BB; boff += 2) {
        hipLaunchKernelGGL(k_gemm1_lif, dim3(HH / 64, NNv / 64, 2), dim3(256), 0, stream,
                           w1f, fc1b, g1, be1, mu1, va1, s1b, s2b, boff);
        hipLaunchKernelGGL(k_gemm2, dim3(CC / 64, LLv / 128, 2), dim3(256), 0, stream,
                           w2f, fc2b, s2b, outp, boff);
    }
}